// Round 1
// baseline (2704.974 us; speedup 1.0000x reference)
//
#include <hip/hip_runtime.h>

#define BB 8
#define CP 21
#define CF 22
#define CLOW 3
#define CHIGH 256
#define WW 80
#define VV 6400
#define EVERT 6320
#define EE 12640
#define TT 16
#define SIGMA_F 0.002f

__device__ __forceinline__ void edge_uv(int e, int& u, int& v) {
  if (e < EVERT) { u = e; v = e + WW; }
  else { int e2 = e - EVERT; int r = e2 / (WW - 1); int c = e2 - r * (WW - 1); u = r * WW + c; v = u + 1; }
}

// ---------------- K1: softmax over 21 channels, per pixel ----------------
__global__ void k_softmax(const float* __restrict__ preds, float* __restrict__ prob) {
  int i = blockIdx.x * blockDim.x + threadIdx.x;
  if (i >= BB * VV) return;
  int b = i / VV, v = i - b * VV;
  const float* p = preds + (size_t)b * CP * VV + v;
  float m = -1e30f;
  #pragma unroll
  for (int c = 0; c < CP; c++) m = fmaxf(m, p[c * VV]);
  float e[CP], s = 0.f;
  #pragma unroll
  for (int c = 0; c < CP; c++) { float x = expf(p[c * VV] - m); e[c] = x; s += x; }
  float inv = 1.f / s;
  float* o = prob + (size_t)b * CP * VV + v;
  #pragma unroll
  for (int c = 0; c < CP; c++) o[c * VV] = e[c] * inv;
}

// ---------------- K2: edge keys (float64 cost, top-50-bits | edge idx) ----------------
__global__ void k_edgekey(const float* __restrict__ low, const float* __restrict__ high,
                          unsigned long long* __restrict__ ekey) {
  int i = blockIdx.x * blockDim.x + threadIdx.x;
  if (i >= TT * EE) return;
  int t = i / EE, e = i - t * EE;
  int u, v; edge_uv(e, u, v);
  double acc = 0.0;
  if (t < BB) {
    const float* emb = low + (size_t)t * CLOW * VV;
    for (int c = 0; c < CLOW; c++) { double d = (double)emb[c * VV + u] - (double)emb[c * VV + v]; acc += d * d; }
  } else {
    const float* emb = high + (size_t)(t - BB) * CHIGH * VV;
    for (int c = 0; c < CHIGH; c++) { double d = (double)emb[c * VV + u] - (double)emb[c * VV + v]; acc += d * d; }
  }
  unsigned long long bits = (unsigned long long)__double_as_longlong(acc);
  ekey[i] = (bits & ~0x3FFFULL) | (unsigned long long)e;
}

// ---------------- K3: parallel Boruvka MST, one block per tree ----------------
__global__ __launch_bounds__(1024) void k_boruvka(const unsigned long long* __restrict__ ekey,
    unsigned long long* __restrict__ best, int* __restrict__ mstU, int* __restrict__ mstV) {
  int t = blockIdx.x;
  const unsigned long long* key = ekey + (size_t)t * EE;
  unsigned long long* bst = best + (size_t)t * VV;
  int* mu = mstU + t * VV;
  int* mv = mstV + t * VV;
  __shared__ int comp[VV];
  __shared__ int tgt[VV];
  __shared__ int changed, moved, cnt;
  int tid = threadIdx.x, nt = blockDim.x;
  for (int v = tid; v < VV; v += nt) comp[v] = v;
  if (tid == 0) cnt = 0;
  __syncthreads();
  for (int round = 0; round < 48; round++) {
    for (int v = tid; v < VV; v += nt) bst[v] = ~0ULL;
    if (tid == 0) changed = 0;
    __syncthreads();
    for (int e = tid; e < EE; e += nt) {
      int u, v; edge_uv(e, u, v);
      int cu = comp[u], cv = comp[v];
      if (cu != cv) { unsigned long long k = key[e]; atomicMin(&bst[cu], k); atomicMin(&bst[cv], k); }
    }
    __syncthreads();
    // pass 1: compute hook targets (reads of comp only; no writes in flight)
    for (int c = tid; c < VV; c += nt) {
      tgt[c] = -1;
      if (comp[c] != c) continue;
      unsigned long long k = bst[c];
      if (k == ~0ULL) continue;
      int e = (int)(k & 0x3FFFULL);
      int u, v; edge_uv(e, u, v);
      int cu = comp[u], cv = comp[v];
      tgt[c] = (cu == c) ? cv : cu;
    }
    __syncthreads();
    // pass 2: hook (writes to comp[c] only by the unique thread owning c)
    for (int c = tid; c < VV; c += nt) {
      int o = tgt[c];
      if (o < 0) continue;
      unsigned long long k = bst[c];
      if (bst[o] == k && c < o) continue;  // mutual minimum edge: smaller id stays root
      comp[c] = o;
      int slot = atomicAdd(&cnt, 1);
      int e = (int)(k & 0x3FFFULL);
      int u, v; edge_uv(e, u, v);
      mu[slot] = u; mv[slot] = v;
      changed = 1;
    }
    __syncthreads();
    if (!changed) break;
    // pointer jumping to full compression
    for (int it = 0; it < 32; it++) {
      if (tid == 0) moved = 0;
      __syncthreads();
      for (int v = tid; v < VV; v += nt) {
        int c = comp[v]; int cc = comp[c];
        if (cc != c) { comp[v] = cc; moved = 1; }
      }
      __syncthreads();
      if (!moved) break;
    }
  }
}

// ---------------- K4: CSR adjacency + BFS rooting at vertex 0 ----------------
__global__ __launch_bounds__(1024) void k_buildtree(const int* __restrict__ mstU, const int* __restrict__ mstV,
    int* __restrict__ parentv, int* __restrict__ order, int* __restrict__ levelptr, int* __restrict__ nlev,
    int* __restrict__ csr_adj) {
  int t = blockIdx.x;
  const int* mu = mstU + t * VV;
  const int* mv = mstV + t * VV;
  int* par = parentv + t * VV;
  int* ord = order + t * VV;
  int* lp = levelptr + t * (VV + 1);
  int* adj = csr_adj + (size_t)t * 2 * VV;
  __shared__ int deg[VV];
  __shared__ int off[VV + 1];
  __shared__ int part[1024];
  __shared__ unsigned int vis[VV / 32];
  __shared__ int tail;
  int tid = threadIdx.x, nt = blockDim.x;
  for (int v = tid; v < VV; v += nt) deg[v] = 0;
  __syncthreads();
  for (int e = tid; e < VV - 1; e += nt) { atomicAdd(&deg[mu[e]], 1); atomicAdd(&deg[mv[e]], 1); }
  __syncthreads();
  const int SCH = (VV + 1023) / 1024;  // 7
  int base = tid * SCH;
  int s = 0;
  #pragma unroll
  for (int k = 0; k < SCH; k++) { int v = base + k; if (v < VV) s += deg[v]; }
  part[tid] = s;
  __syncthreads();
  for (int d = 1; d < 1024; d <<= 1) {
    int add = (tid >= d) ? part[tid - d] : 0;
    __syncthreads();
    part[tid] += add;
    __syncthreads();
  }
  int ex = part[tid] - s;
  #pragma unroll
  for (int k = 0; k < SCH; k++) { int v = base + k; if (v < VV) { off[v] = ex; ex += deg[v]; } }
  if (tid == 1023) off[VV] = ex;
  __syncthreads();
  for (int v = tid; v < VV; v += nt) deg[v] = off[v];  // reuse as cursors
  __syncthreads();
  for (int e = tid; e < VV - 1; e += nt) {
    int u = mu[e], v = mv[e];
    adj[atomicAdd(&deg[u], 1)] = v;
    adj[atomicAdd(&deg[v], 1)] = u;
  }
  for (int i = tid; i < VV / 32; i += nt) vis[i] = 0;
  __syncthreads();
  if (tid == 0) { ord[0] = 0; par[0] = 0; vis[0] = 1u; tail = 1; lp[0] = 0; lp[1] = 1; }
  __syncthreads();
  int head = 0, levelEnd = 1, lev = 1;
  while (levelEnd < VV) {
    for (int i = head + tid; i < levelEnd; i += nt) {
      int u = ord[i];
      for (int a = off[u]; a < off[u + 1]; a++) {
        int n = adj[a];
        unsigned int m = 1u << (n & 31);
        if ((atomicOr(&vis[n >> 5], m) & m) == 0) {
          par[n] = u;
          ord[atomicAdd(&tail, 1)] = n;
        }
      }
    }
    __syncthreads();
    int newEnd = tail;
    if (tid == 0) lp[lev + 1] = newEnd;
    lev++;
    if (newEnd == levelEnd) break;  // safety (should not happen: tree is spanning)
    head = levelEnd; levelEnd = newEnd;
    __syncthreads();  // protect `tail` reads from next iteration's atomicAdds
  }
  if (tid == 0) nlev[t] = lev;
}

// ---------------- K5: per-vertex weight to parent, f32 (matches reference) ----------------
__global__ void k_weights(const float* __restrict__ low, const float* __restrict__ high,
                          const int* __restrict__ parentv, float* __restrict__ wvp) {
  int i = blockIdx.x * blockDim.x + threadIdx.x;
  if (i >= TT * VV) return;
  int t = i / VV, v = i - t * VV;
  int p = parentv[i];
  float d = 0.f;
  if (t < BB) {
    const float* emb = low + (size_t)t * CLOW * VV;
    for (int c = 0; c < CLOW; c++) { float x = emb[c * VV + v] - emb[c * VV + p]; d += x * x; }
  } else {
    const float* emb = high + (size_t)(t - BB) * CHIGH * VV;
    for (int c = 0; c < CHIGH; c++) { float x = emb[c * VV + v] - emb[c * VV + p]; d += x * x; }
  }
  wvp[i] = expf(-d / SIGMA_F);
}

// ---------------- K6: exact normalized tree filter (level-parallel up/down) ----------------
__global__ __launch_bounds__(1024) void k_filter(const float* __restrict__ F, float* __restrict__ O,
    const float* __restrict__ wvp, const int* __restrict__ parentv, const int* __restrict__ order,
    const int* __restrict__ levelptr, const int* __restrict__ nlev,
    float* __restrict__ S, float* __restrict__ A, int treeBase) {
  int b = blockIdx.x;
  int t = treeBase + b;
  const int* par = parentv + t * VV;
  const int* ord = order + t * VV;
  const int* lp = levelptr + t * (VV + 1);
  const float* w = wvp + t * VV;
  float* Sb = S + (size_t)b * CF * VV;
  float* Ab = A + (size_t)b * CF * VV;
  const float* Fb = F + (size_t)b * CP * VV;
  float* Ob = O + (size_t)b * CP * VV;
  int tid = threadIdx.x, nt = blockDim.x;
  int NL = nlev[t];
  for (int i = tid; i < CP * VV; i += nt) Sb[i] = Fb[i];
  for (int i = tid; i < VV; i += nt) Sb[CP * VV + i] = 1.0f;
  __syncthreads();
  // up-sweep: deepest level first; children are exactly one level deeper than parent
  for (int l = NL - 1; l >= 1; l--) {
    int s0 = lp[l], s1 = lp[l + 1];
    int n = s1 - s0;
    for (int i = tid; i < n * CF; i += nt) {
      int vi = i / CF, ch = i - vi * CF;
      int v = ord[s0 + vi];
      int p = par[v];
      atomicAdd(&Sb[ch * VV + p], w[v] * Sb[ch * VV + v]);
    }
    __syncthreads();
  }
  // down-sweep
  for (int ch = tid; ch < CF; ch += nt) Ab[ch * VV + 0] = Sb[ch * VV + 0];
  __syncthreads();
  for (int l = 1; l < NL; l++) {
    int s0 = lp[l], s1 = lp[l + 1];
    int n = s1 - s0;
    for (int i = tid; i < n * CF; i += nt) {
      int vi = i / CF, ch = i - vi * CF;
      int v = ord[s0 + vi];
      int p = par[v];
      float wv_ = w[v];
      float sv = Sb[ch * VV + v];
      Ab[ch * VV + v] = sv + wv_ * (Ab[ch * VV + p] - wv_ * sv);
    }
    __syncthreads();
  }
  for (int i = tid; i < CP * VV; i += nt) {
    int ch = i / VV, v = i - ch * VV;
    Ob[i] = Ab[i] / Ab[CP * VV + v];
  }
}

// ---------------- K7: ROI-masked L1 loss reduction ----------------
__global__ void k_loss(const float* __restrict__ prob, const float* __restrict__ AS2,
                       const int* __restrict__ roi, double* __restrict__ acc) {
  int i = blockIdx.x * blockDim.x + threadIdx.x;
  int tid = threadIdx.x;
  double s = 0.0, n = 0.0;
  if (i < BB * VV) {
    int b = i / VV, v = i - b * VV;
    if (roi[i] != 0) {
      n = 1.0;
      const float* pb = prob + (size_t)b * CP * VV + v;
      const float* ab = AS2 + (size_t)b * CP * VV + v;
      float ls = 0.f;
      #pragma unroll
      for (int c = 0; c < CP; c++) ls += fabsf(pb[c * VV] - ab[c * VV]);
      s = (double)ls;
    }
  }
  __shared__ double rs[256], rn[256];
  rs[tid] = s; rn[tid] = n;
  __syncthreads();
  for (int d = 128; d > 0; d >>= 1) {
    if (tid < d) { rs[tid] += rs[tid + d]; rn[tid] += rn[tid + d]; }
    __syncthreads();
  }
  if (tid == 0) { atomicAdd(&acc[0], rs[0]); atomicAdd(&acc[1], rn[0]); }
}

__global__ void k_finalize(const double* __restrict__ acc, float* __restrict__ out) {
  out[0] = (acc[1] > 0.0) ? (float)(acc[0] / acc[1]) : 0.0f;
}

extern "C" void kernel_launch(void* const* d_in, const int* in_sizes, int n_in,
                              void* d_out, int out_size, void* d_ws, size_t ws_size,
                              hipStream_t stream) {
  const float* preds = (const float*)d_in[0];
  const float* low   = (const float*)d_in[1];
  const float* high  = (const float*)d_in[2];
  const int*   roi   = (const int*)d_in[3];
  float* out = (float*)d_out;

  char* w = (char*)d_ws;
  size_t off = 0;
  auto alloc = [&](size_t bytes) -> void* {
    void* p = w + off;
    off += (bytes + 255) & ~(size_t)255;
    return p;
  };
  float* prob = (float*)alloc((size_t)BB * CP * VV * 4);
  float* AS1  = (float*)alloc((size_t)BB * CP * VV * 4);
  float* AS2  = (float*)alloc((size_t)BB * CP * VV * 4);
  float* S    = (float*)alloc((size_t)BB * CF * VV * 4);
  float* A    = (float*)alloc((size_t)BB * CF * VV * 4);
  unsigned long long* ekey = (unsigned long long*)alloc((size_t)TT * EE * 8);
  unsigned long long* best = (unsigned long long*)alloc((size_t)TT * VV * 8);
  int* mstU    = (int*)alloc((size_t)TT * VV * 4);
  int* mstV    = (int*)alloc((size_t)TT * VV * 4);
  int* parentv = (int*)alloc((size_t)TT * VV * 4);
  int* order   = (int*)alloc((size_t)TT * VV * 4);
  int* levelptr= (int*)alloc((size_t)TT * (VV + 1) * 4);
  int* nlev    = (int*)alloc((size_t)TT * 4);
  int* csr_adj = (int*)alloc((size_t)TT * 2 * VV * 4);
  float* wvp   = (float*)alloc((size_t)TT * VV * 4);
  double* acc  = (double*)alloc(16);

  hipMemsetAsync(acc, 0, 16, stream);

  k_softmax<<<(BB * VV + 255) / 256, 256, 0, stream>>>(preds, prob);
  k_edgekey<<<(TT * EE + 255) / 256, 256, 0, stream>>>(low, high, ekey);
  k_boruvka<<<TT, 1024, 0, stream>>>(ekey, best, mstU, mstV);
  k_buildtree<<<TT, 1024, 0, stream>>>(mstU, mstV, parentv, order, levelptr, nlev, csr_adj);
  k_weights<<<(TT * VV + 255) / 256, 256, 0, stream>>>(low, high, parentv, wvp);
  k_filter<<<BB, 1024, 0, stream>>>(prob, AS1, wvp, parentv, order, levelptr, nlev, S, A, 0);
  k_filter<<<BB, 1024, 0, stream>>>(AS1, AS2, wvp, parentv, order, levelptr, nlev, S, A, BB);
  k_loss<<<(BB * VV + 255) / 256, 256, 0, stream>>>(prob, AS2, roi, acc);
  k_finalize<<<1, 1, 0, stream>>>(acc, out);
}

// Round 2
// 998.138 us; speedup vs baseline: 2.7100x; 2.7100x over previous
//
#include <hip/hip_runtime.h>

#define BB 8
#define CP 21
#define CF 22
#define CLOW 3
#define CHIGH 256
#define WW 80
#define VV 6400
#define EVERT 6320
#define EE 12640
#define TT 16
#define SIGMA_F 0.002f

__device__ __forceinline__ void edge_uv(int e, int& u, int& v) {
  if (e < EVERT) { u = e; v = e + WW; }
  else { int e2 = e - EVERT; int r = e2 / (WW - 1); int c = e2 - r * (WW - 1); u = r * WW + c; v = u + 1; }
}

// ---------------- K1: softmax over 21 channels, per pixel ----------------
__global__ void k_softmax(const float* __restrict__ preds, float* __restrict__ prob) {
  int i = blockIdx.x * blockDim.x + threadIdx.x;
  if (i >= BB * VV) return;
  int b = i / VV, v = i - b * VV;
  const float* p = preds + (size_t)b * CP * VV + v;
  float m = -1e30f;
  #pragma unroll
  for (int c = 0; c < CP; c++) m = fmaxf(m, p[c * VV]);
  float e[CP], s = 0.f;
  #pragma unroll
  for (int c = 0; c < CP; c++) { float x = expf(p[c * VV] - m); e[c] = x; s += x; }
  float inv = 1.f / s;
  float* o = prob + (size_t)b * CP * VV + v;
  #pragma unroll
  for (int c = 0; c < CP; c++) o[c * VV] = e[c] * inv;
}

// ---------------- K2: edge keys (float64 cost, top-50-bits | edge idx) ----------------
__global__ void k_edgekey(const float* __restrict__ low, const float* __restrict__ high,
                          unsigned long long* __restrict__ ekey) {
  int i = blockIdx.x * blockDim.x + threadIdx.x;
  if (i >= TT * EE) return;
  int t = i / EE, e = i - t * EE;
  int u, v; edge_uv(e, u, v);
  double acc = 0.0;
  if (t < BB) {
    const float* emb = low + (size_t)t * CLOW * VV;
    for (int c = 0; c < CLOW; c++) { double d = (double)emb[c * VV + u] - (double)emb[c * VV + v]; acc += d * d; }
  } else {
    const float* emb = high + (size_t)(t - BB) * CHIGH * VV;
    for (int c = 0; c < CHIGH; c++) { double d = (double)emb[c * VV + u] - (double)emb[c * VV + v]; acc += d * d; }
  }
  unsigned long long bits = (unsigned long long)__double_as_longlong(acc);
  ekey[i] = (bits & ~0x3FFFULL) | (unsigned long long)e;
}

// ---------------- K3: parallel Boruvka MST, one block per tree (best[] in LDS) ----------------
__global__ __launch_bounds__(1024) void k_boruvka(const unsigned long long* __restrict__ ekey,
    int* __restrict__ mstU, int* __restrict__ mstV) {
  int t = blockIdx.x;
  const unsigned long long* key = ekey + (size_t)t * EE;
  int* mu = mstU + t * VV;
  int* mv = mstV + t * VV;
  __shared__ int comp[VV];
  __shared__ int tgt[VV];
  __shared__ unsigned long long bst[VV];
  __shared__ int changed, moved, cnt;
  int tid = threadIdx.x, nt = blockDim.x;
  for (int v = tid; v < VV; v += nt) comp[v] = v;
  if (tid == 0) cnt = 0;
  __syncthreads();
  for (int round = 0; round < 48; round++) {
    for (int v = tid; v < VV; v += nt) bst[v] = ~0ULL;
    if (tid == 0) changed = 0;
    __syncthreads();
    for (int e = tid; e < EE; e += nt) {
      int u, v; edge_uv(e, u, v);
      int cu = comp[u], cv = comp[v];
      if (cu != cv) { unsigned long long k = key[e]; atomicMin(&bst[cu], k); atomicMin(&bst[cv], k); }
    }
    __syncthreads();
    // pass 1: compute hook targets (reads of comp only)
    for (int c = tid; c < VV; c += nt) {
      tgt[c] = -1;
      if (comp[c] != c) continue;
      unsigned long long k = bst[c];
      if (k == ~0ULL) continue;
      int e = (int)(k & 0x3FFFULL);
      int u, v; edge_uv(e, u, v);
      int cu = comp[u], cv = comp[v];
      tgt[c] = (cu == c) ? cv : cu;
    }
    __syncthreads();
    // pass 2: hook
    for (int c = tid; c < VV; c += nt) {
      int o = tgt[c];
      if (o < 0) continue;
      unsigned long long k = bst[c];
      if (bst[o] == k && c < o) continue;  // mutual minimum edge: smaller id stays root
      comp[c] = o;
      int slot = atomicAdd(&cnt, 1);
      int e = (int)(k & 0x3FFFULL);
      int u, v; edge_uv(e, u, v);
      mu[slot] = u; mv[slot] = v;
      changed = 1;
    }
    __syncthreads();
    if (!changed) break;
    // pointer jumping
    for (int it = 0; it < 32; it++) {
      if (tid == 0) moved = 0;
      __syncthreads();
      for (int v = tid; v < VV; v += nt) {
        int c = comp[v]; int cc = comp[c];
        if (cc != c) { comp[v] = cc; moved = 1; }
      }
      __syncthreads();
      if (!moved) break;
    }
  }
}

// ---------------- K4: CSR adjacency (LDS) + BFS rooting at vertex 0 ----------------
// Outputs (position space): ordG[j]=vertex at BFS pos j, spG[j]=BFS pos of parent,
// pvG[j]=vertex id of parent, lpG level ranges, nlev.
__global__ __launch_bounds__(1024) void k_buildtree(const int* __restrict__ mstU, const int* __restrict__ mstV,
    int* __restrict__ ordG, int* __restrict__ spG, int* __restrict__ pvG,
    int* __restrict__ lpG, int* __restrict__ nlevG) {
  int t = blockIdx.x;
  const int* mu = mstU + t * VV;
  const int* mv = mstV + t * VV;
  int* lp = lpG + t * (VV + 1);
  __shared__ int deg[VV];
  __shared__ int off[VV + 1];
  __shared__ int adj[2 * VV];
  __shared__ int ord[VV];
  __shared__ int part[1024];
  __shared__ unsigned int vis[VV / 32];
  __shared__ int tail;
  int tid = threadIdx.x, nt = blockDim.x;
  for (int v = tid; v < VV; v += nt) deg[v] = 0;
  __syncthreads();
  for (int e = tid; e < VV - 1; e += nt) { atomicAdd(&deg[mu[e]], 1); atomicAdd(&deg[mv[e]], 1); }
  __syncthreads();
  const int SCH = (VV + 1023) / 1024;  // 7
  int base = tid * SCH;
  int s = 0;
  #pragma unroll
  for (int k = 0; k < SCH; k++) { int v = base + k; if (v < VV) s += deg[v]; }
  part[tid] = s;
  __syncthreads();
  for (int d = 1; d < 1024; d <<= 1) {
    int add = (tid >= d) ? part[tid - d] : 0;
    __syncthreads();
    part[tid] += add;
    __syncthreads();
  }
  int ex = part[tid] - s;
  #pragma unroll
  for (int k = 0; k < SCH; k++) { int v = base + k; if (v < VV) { off[v] = ex; ex += deg[v]; } }
  if (tid == 1023) off[VV] = ex;
  __syncthreads();
  for (int v = tid; v < VV; v += nt) deg[v] = off[v];  // reuse as cursors
  __syncthreads();
  for (int e = tid; e < VV - 1; e += nt) {
    int u = mu[e], v = mv[e];
    adj[atomicAdd(&deg[u], 1)] = v;
    adj[atomicAdd(&deg[v], 1)] = u;
  }
  for (int i = tid; i < VV / 32; i += nt) vis[i] = 0;
  __syncthreads();
  if (tid == 0) {
    ord[0] = 0; vis[0] = 1u; tail = 1;
    lp[0] = 0; lp[1] = 1;
    spG[t * VV + 0] = 0; pvG[t * VV + 0] = 0;
  }
  __syncthreads();
  int head = 0, levelEnd = 1, lev = 1;
  while (levelEnd < VV) {
    for (int i = head + tid; i < levelEnd; i += nt) {
      int u = ord[i];
      for (int a = off[u]; a < off[u + 1]; a++) {
        int n = adj[a];
        unsigned int m = 1u << (n & 31);
        if ((atomicOr(&vis[n >> 5], m) & m) == 0) {
          int pos = atomicAdd(&tail, 1);
          ord[pos] = n;
          spG[t * VV + pos] = i;
          pvG[t * VV + pos] = u;
        }
      }
    }
    __syncthreads();
    int newEnd = tail;
    if (tid == 0) lp[lev + 1] = newEnd;
    lev++;
    if (newEnd == levelEnd) break;  // safety
    head = levelEnd; levelEnd = newEnd;
    __syncthreads();
  }
  if (tid == 0) nlevG[t] = lev;
  __syncthreads();
  for (int v = tid; v < VV; v += nt) ordG[t * VV + v] = ord[v];
}

// ---------------- K5: per-position weight to parent, f32, BFS-sorted ----------------
__global__ void k_weights(const float* __restrict__ low, const float* __restrict__ high,
                          const int* __restrict__ ordG, const int* __restrict__ pvG,
                          float* __restrict__ wvp) {
  int i = blockIdx.x * blockDim.x + threadIdx.x;
  if (i >= TT * VV) return;
  int t = i / VV;
  int v = ordG[i], p = pvG[i];
  float d = 0.f;
  if (t < BB) {
    const float* emb = low + (size_t)t * CLOW * VV;
    for (int c = 0; c < CLOW; c++) { float x = emb[c * VV + v] - emb[c * VV + p]; d += x * x; }
  } else {
    const float* emb = high + (size_t)(t - BB) * CHIGH * VV;
    for (int c = 0; c < CHIGH; c++) { float x = emb[c * VV + v] - emb[c * VV + p]; d += x * x; }
  }
  wvp[i] = expf(-d / SIGMA_F);
}

// ---------------- K6: tree filter, one block per (tree,channel), LDS-resident ----------------
// mode 0: input F has CP channels (gather raw).  mode 1: input has CF channels,
// gather F[ch]/F[CP] (normalize previous stage at read time).
// Output: Araw[b][CF][VV] in vertex space (unnormalized filtered values + norm channel).
__global__ __launch_bounds__(256) void k_filter_pc(const float* __restrict__ Fsrc, float* __restrict__ Araw,
    const float* __restrict__ wvp, const int* __restrict__ ordG, const int* __restrict__ spG,
    const int* __restrict__ lpG, const int* __restrict__ nlevG, int treeBase) {
  int blk = blockIdx.x;
  int b = blk / CF, ch = blk - b * CF;
  int t = treeBase + b;
  __shared__ float S[VV];
  __shared__ float A[VV];
  __shared__ float w[VV];
  __shared__ unsigned short sp[VV];
  __shared__ int lpS[VV + 1];
  const int* ord = ordG + t * VV;
  const int* spt = spG + t * VV;
  const float* wsrc = wvp + t * VV;
  const int* lp = lpG + t * (VV + 1);
  int tid = threadIdx.x, nt = blockDim.x;
  int NL = nlevG[t];
  for (int j = tid; j <= NL; j += nt) lpS[j] = lp[j];
  const bool norm_in = (treeBase != 0);
  for (int j = tid; j < VV; j += nt) {
    sp[j] = (unsigned short)spt[j];
    w[j] = wsrc[j];
    float val;
    if (ch < CP) {
      int v = ord[j];
      if (!norm_in) val = Fsrc[((size_t)b * CP + ch) * VV + v];
      else          val = Fsrc[((size_t)b * CF + ch) * VV + v] / Fsrc[((size_t)b * CF + CP) * VV + v];
    } else val = 1.0f;
    S[j] = val;
  }
  __syncthreads();
  // up-sweep (children are exactly one level deeper than parents)
  for (int l = NL - 1; l >= 1; l--) {
    int s0 = lpS[l], s1 = lpS[l + 1];
    for (int j = s0 + tid; j < s1; j += nt) {
      atomicAdd(&S[sp[j]], w[j] * S[j]);
    }
    __syncthreads();
  }
  if (tid == 0) A[0] = S[0];
  __syncthreads();
  // down-sweep
  for (int l = 1; l < NL; l++) {
    int s0 = lpS[l], s1 = lpS[l + 1];
    for (int j = s0 + tid; j < s1; j += nt) {
      float wv = w[j], sv = S[j];
      A[j] = sv + wv * (A[sp[j]] - wv * sv);
    }
    __syncthreads();
  }
  // scatter to vertex space
  float* Ob = Araw + ((size_t)b * CF + ch) * VV;
  for (int j = tid; j < VV; j += nt) Ob[ord[j]] = A[j];
}

// ---------------- K7: ROI-masked L1 loss reduction (fused normalize of stage 2) ----------------
__global__ void k_loss(const float* __restrict__ prob, const float* __restrict__ Araw2,
                       const int* __restrict__ roi, double* __restrict__ acc) {
  int i = blockIdx.x * blockDim.x + threadIdx.x;
  int tid = threadIdx.x;
  double s = 0.0, n = 0.0;
  if (i < BB * VV) {
    int b = i / VV, v = i - b * VV;
    if (roi[i] != 0) {
      n = 1.0;
      const float* pb = prob + (size_t)b * CP * VV + v;
      const float* ab = Araw2 + (size_t)b * CF * VV + v;
      float inv = 1.0f / ab[CP * VV];
      float ls = 0.f;
      #pragma unroll
      for (int c = 0; c < CP; c++) ls += fabsf(pb[c * VV] - ab[c * VV] * inv);
      s = (double)ls;
    }
  }
  __shared__ double rs[256], rn[256];
  rs[tid] = s; rn[tid] = n;
  __syncthreads();
  for (int d = 128; d > 0; d >>= 1) {
    if (tid < d) { rs[tid] += rs[tid + d]; rn[tid] += rn[tid + d]; }
    __syncthreads();
  }
  if (tid == 0) { atomicAdd(&acc[0], rs[0]); atomicAdd(&acc[1], rn[0]); }
}

__global__ void k_finalize(const double* __restrict__ acc, float* __restrict__ out) {
  out[0] = (acc[1] > 0.0) ? (float)(acc[0] / acc[1]) : 0.0f;
}

extern "C" void kernel_launch(void* const* d_in, const int* in_sizes, int n_in,
                              void* d_out, int out_size, void* d_ws, size_t ws_size,
                              hipStream_t stream) {
  const float* preds = (const float*)d_in[0];
  const float* low   = (const float*)d_in[1];
  const float* high  = (const float*)d_in[2];
  const int*   roi   = (const int*)d_in[3];
  float* out = (float*)d_out;

  char* w = (char*)d_ws;
  size_t off = 0;
  auto alloc = [&](size_t bytes) -> void* {
    void* p = w + off;
    off += (bytes + 255) & ~(size_t)255;
    return p;
  };
  float* prob  = (float*)alloc((size_t)BB * CP * VV * 4);
  float* Araw1 = (float*)alloc((size_t)BB * CF * VV * 4);
  float* Araw2 = (float*)alloc((size_t)BB * CF * VV * 4);
  unsigned long long* ekey = (unsigned long long*)alloc((size_t)TT * EE * 8);
  int* mstU = (int*)alloc((size_t)TT * VV * 4);
  int* mstV = (int*)alloc((size_t)TT * VV * 4);
  int* ordG = (int*)alloc((size_t)TT * VV * 4);
  int* spG  = (int*)alloc((size_t)TT * VV * 4);
  int* pvG  = (int*)alloc((size_t)TT * VV * 4);
  int* lpG  = (int*)alloc((size_t)TT * (VV + 1) * 4);
  int* nlev = (int*)alloc((size_t)TT * 4);
  float* wvp = (float*)alloc((size_t)TT * VV * 4);
  double* acc = (double*)alloc(16);

  hipMemsetAsync(acc, 0, 16, stream);

  k_softmax<<<(BB * VV + 255) / 256, 256, 0, stream>>>(preds, prob);
  k_edgekey<<<(TT * EE + 255) / 256, 256, 0, stream>>>(low, high, ekey);
  k_boruvka<<<TT, 1024, 0, stream>>>(ekey, mstU, mstV);
  k_buildtree<<<TT, 1024, 0, stream>>>(mstU, mstV, ordG, spG, pvG, lpG, nlev);
  k_weights<<<(TT * VV + 255) / 256, 256, 0, stream>>>(low, high, ordG, pvG, wvp);
  k_filter_pc<<<BB * CF, 256, 0, stream>>>(prob,  Araw1, wvp, ordG, spG, lpG, nlev, 0);
  k_filter_pc<<<BB * CF, 256, 0, stream>>>(Araw1, Araw2, wvp, ordG, spG, lpG, nlev, BB);
  k_loss<<<(BB * VV + 255) / 256, 256, 0, stream>>>(prob, Araw2, roi, acc);
  k_finalize<<<1, 1, 0, stream>>>(acc, out);
}

// Round 3
// 598.408 us; speedup vs baseline: 4.5203x; 1.6680x over previous
//
#include <hip/hip_runtime.h>

#define BB 8
#define CP 21
#define CF 22
#define CLOW 3
#define CHIGH 256
#define WW 80
#define VV 6400
#define EVERT 6320
#define EE 12640
#define TT 16
#define SIGMA_F 0.002f

#define NE (VV - 1)        // tree edges
#define NA (2 * NE)        // Euler arcs = 12798
#define NILA 0xFFFFu

__device__ __forceinline__ void edge_uv(int e, int& u, int& v) {
  if (e < EVERT) { u = e; v = e + WW; }
  else { int e2 = e - EVERT; int r = e2 / (WW - 1); int c = e2 - r * (WW - 1); u = r * WW + c; v = u + 1; }
}

// ---------------- K1: softmax over 21 channels, per pixel ----------------
__global__ void k_softmax(const float* __restrict__ preds, float* __restrict__ prob) {
  int i = blockIdx.x * blockDim.x + threadIdx.x;
  if (i >= BB * VV) return;
  int b = i / VV, v = i - b * VV;
  const float* p = preds + (size_t)b * CP * VV + v;
  float m = -1e30f;
  #pragma unroll
  for (int c = 0; c < CP; c++) m = fmaxf(m, p[c * VV]);
  float e[CP], s = 0.f;
  #pragma unroll
  for (int c = 0; c < CP; c++) { float x = expf(p[c * VV] - m); e[c] = x; s += x; }
  float inv = 1.f / s;
  float* o = prob + (size_t)b * CP * VV + v;
  #pragma unroll
  for (int c = 0; c < CP; c++) o[c * VV] = e[c] * inv;
}

// ---------------- K2: edge keys (float64 cost, top-50-bits | edge idx) ----------------
__global__ void k_edgekey(const float* __restrict__ low, const float* __restrict__ high,
                          unsigned long long* __restrict__ ekey) {
  int i = blockIdx.x * blockDim.x + threadIdx.x;
  if (i >= TT * EE) return;
  int t = i / EE, e = i - t * EE;
  int u, v; edge_uv(e, u, v);
  double acc = 0.0;
  if (t < BB) {
    const float* emb = low + (size_t)t * CLOW * VV;
    for (int c = 0; c < CLOW; c++) { double d = (double)emb[c * VV + u] - (double)emb[c * VV + v]; acc += d * d; }
  } else {
    const float* emb = high + (size_t)(t - BB) * CHIGH * VV;
    for (int c = 0; c < CHIGH; c++) { double d = (double)emb[c * VV + u] - (double)emb[c * VV + v]; acc += d * d; }
  }
  unsigned long long bits = (unsigned long long)__double_as_longlong(acc);
  ekey[i] = (bits & ~0x3FFFULL) | (unsigned long long)e;
}

// ---------------- K3: parallel Boruvka MST, one block per tree (best[] in LDS) ----------------
__global__ __launch_bounds__(1024) void k_boruvka(const unsigned long long* __restrict__ ekey,
    int* __restrict__ mstU, int* __restrict__ mstV) {
  int t = blockIdx.x;
  const unsigned long long* key = ekey + (size_t)t * EE;
  int* mu = mstU + t * VV;
  int* mv = mstV + t * VV;
  __shared__ int comp[VV];
  __shared__ int tgt[VV];
  __shared__ unsigned long long bst[VV];
  __shared__ int changed, moved, cnt;
  int tid = threadIdx.x, nt = blockDim.x;
  for (int v = tid; v < VV; v += nt) comp[v] = v;
  if (tid == 0) cnt = 0;
  __syncthreads();
  for (int round = 0; round < 48; round++) {
    for (int v = tid; v < VV; v += nt) bst[v] = ~0ULL;
    if (tid == 0) changed = 0;
    __syncthreads();
    for (int e = tid; e < EE; e += nt) {
      int u, v; edge_uv(e, u, v);
      int cu = comp[u], cv = comp[v];
      if (cu != cv) { unsigned long long k = key[e]; atomicMin(&bst[cu], k); atomicMin(&bst[cv], k); }
    }
    __syncthreads();
    for (int c = tid; c < VV; c += nt) {
      tgt[c] = -1;
      if (comp[c] != c) continue;
      unsigned long long k = bst[c];
      if (k == ~0ULL) continue;
      int e = (int)(k & 0x3FFFULL);
      int u, v; edge_uv(e, u, v);
      int cu = comp[u], cv = comp[v];
      tgt[c] = (cu == c) ? cv : cu;
    }
    __syncthreads();
    for (int c = tid; c < VV; c += nt) {
      int o = tgt[c];
      if (o < 0) continue;
      unsigned long long k = bst[c];
      if (bst[o] == k && c < o) continue;  // mutual minimum edge: smaller id stays root
      comp[c] = o;
      int slot = atomicAdd(&cnt, 1);
      int e = (int)(k & 0x3FFFULL);
      int u, v; edge_uv(e, u, v);
      mu[slot] = u; mv[slot] = v;
      changed = 1;
    }
    __syncthreads();
    if (!changed) break;
    for (int it = 0; it < 32; it++) {
      if (tid == 0) moved = 0;
      __syncthreads();
      for (int v = tid; v < VV; v += nt) {
        int c = comp[v]; int cc = comp[c];
        if (cc != c) { comp[v] = cc; moved = 1; }
      }
      __syncthreads();
      if (!moved) break;
    }
  }
}

// ---------------- K4: Euler-tour tree rooting (replaces BFS) ----------------
// Outputs: ordG[j]=vertex at position j (levels contiguous, sorted by depth),
// spG[j]=position of parent, pvG[j]=vertex id of parent, lpG level starts, nlevG.
__global__ __launch_bounds__(1024) void k_buildtree(const int* __restrict__ mstU, const int* __restrict__ mstV,
    int* __restrict__ ordG, int* __restrict__ spG, int* __restrict__ pvG,
    int* __restrict__ lpG, int* __restrict__ nlevG) {
  int t = blockIdx.x;
  const int* mu = mstU + t * VV;
  const int* mv = mstV + t * VV;
  int tid = threadIdx.x, nt = blockDim.x;

  __shared__ int buf4[32004];            // 128016-byte phase-overlapped arena
  char* buf = (char*)buf4;
  __shared__ int part[1024];
  __shared__ int a0s, lasts, smaxd;

  // Phase A regions
  int* deg = (int*)(buf + 0);                       // int[VV)            [0,25600)
  int* off = (int*)(buf + 25600);                   // int[VV+1]          [25600,51204)
  unsigned short* adjA = (unsigned short*)(buf + 51208);   // ushort[NA]  [51208,76804)
  unsigned short* succ = (unsigned short*)(buf + 76808);   // ushort[NA]  [76808,102404)
  // Phase B (ranking) regions
  unsigned short* r_a = (unsigned short*)(buf + 0);        // ushort[NA]  [0,25596)
  unsigned short* r_b = (unsigned short*)(buf + 25604);    // ushort[NA]  [25604,51200)
  unsigned short* nx_b = (unsigned short*)(buf + 102408);  // ushort[NA]  [102408,128004)
  // Phase C regions
  short* tv = (short*)(buf + 51208);                       // short[NA]   (adjA dead)
  unsigned short* parentS = (unsigned short*)(buf + 76808);// ushort[VV]  (succ dead)
  unsigned short* depthS  = (unsigned short*)(buf + 89608);// ushort[VV]
  // Phase D regions
  int* lev = (int*)(buf + 0);                      // int[VV+1]  (r_a dead)
  int* cur = (int*)(buf + 25604);                  // int[VV]    (r_b dead)
  unsigned short* ordS = (unsigned short*)(buf + 102408);  // ushort[VV] (nx_b dead)
  unsigned short* posS = (unsigned short*)(buf + 115208);  // ushort[VV]

  // ---- Phase A: CSR + Euler successors ----
  for (int v = tid; v < VV; v += nt) deg[v] = 0;
  __syncthreads();
  for (int e = tid; e < NE; e += nt) { atomicAdd(&deg[mu[e]], 1); atomicAdd(&deg[mv[e]], 1); }
  __syncthreads();
  {
    const int SCH = 7;
    int base = tid * SCH;
    int s = 0;
    #pragma unroll
    for (int k = 0; k < SCH; k++) { int v = base + k; if (v < VV) s += deg[v]; }
    part[tid] = s;
    __syncthreads();
    for (int d = 1; d < 1024; d <<= 1) {
      int add = (tid >= d) ? part[tid - d] : 0;
      __syncthreads();
      part[tid] += add;
      __syncthreads();
    }
    int ex = part[tid] - s;
    #pragma unroll
    for (int k = 0; k < SCH; k++) { int v = base + k; if (v < VV) { off[v] = ex; ex += deg[v]; } }
    if (tid == 1023) off[VV] = ex;
  }
  __syncthreads();
  for (int v = tid; v < VV; v += nt) deg[v] = off[v];   // cursors
  __syncthreads();
  for (int e = tid; e < NE; e += nt) {
    int u = mu[e], v = mv[e];
    adjA[atomicAdd(&deg[u], 1)] = (unsigned short)(2 * e);       // arc u->v
    adjA[atomicAdd(&deg[v], 1)] = (unsigned short)(2 * e + 1);   // arc v->u
  }
  __syncthreads();
  for (int v = tid; v < VV; v += nt) {
    int b0 = off[v], dv = off[v + 1] - b0;
    for (int k = 0; k < dv; k++) {
      unsigned short a = adjA[b0 + k];
      unsigned short b = adjA[b0 + ((k + 1 == dv) ? 0 : k + 1)];
      succ[a ^ 1] = b;
    }
  }
  if (tid == 0) {
    a0s = adjA[off[0]];
    lasts = adjA[off[0] + (off[1] - off[0]) - 1] ^ 1;  // last arc entering root
    smaxd = 0;
  }
  __syncthreads();
  if (tid == 0) succ[lasts] = (unsigned short)NILA;
  __syncthreads();
  // ---- Phase B: list ranking (r = #arcs strictly after) ----
  for (int a = tid; a < NA; a += nt) r_a[a] = (succ[a] == (unsigned short)NILA) ? 0 : 1;
  __syncthreads();
  {
    unsigned short *rx = r_a, *ry = r_b, *nxp = succ, *nyp = nx_b;
    for (int rd = 0; rd < 14; rd++) {
      for (int a = tid; a < NA; a += nt) {
        unsigned short n = nxp[a];
        if (n == (unsigned short)NILA) { ry[a] = rx[a]; nyp[a] = (unsigned short)NILA; }
        else { ry[a] = rx[a] + rx[n]; nyp[a] = nxp[n]; }
      }
      __syncthreads();
      unsigned short* tp;
      tp = rx; rx = ry; ry = tp;
      tp = nxp; nxp = nyp; nyp = tp;
    }
    // 14 rounds (even) -> final ranks in r_a
  }
  // ---- Phase C: tour values, depth scan, parent extraction ----
  for (int a = tid; a < NA; a += nt) {
    int p = (NA - 1) - (int)r_a[a];
    tv[p] = (r_a[a] > r_a[a ^ 1]) ? (short)1 : (short)-1;
  }
  __syncthreads();
  {
    const int SCH = 13;
    int base = tid * SCH;
    int lim = base + SCH; if (lim > NA) lim = NA;
    int s = 0;
    for (int j = base; j < lim; j++) s += tv[j];
    part[tid] = s;
    __syncthreads();
    for (int d = 1; d < 1024; d <<= 1) {
      int add = (tid >= d) ? part[tid - d] : 0;
      __syncthreads();
      part[tid] += add;
      __syncthreads();
    }
    int run = part[tid] - s;
    for (int j = base; j < lim; j++) { run += tv[j]; tv[j] = (short)run; }
  }
  __syncthreads();
  for (int a = tid; a < NA; a += nt) {
    if (r_a[a] > r_a[a ^ 1]) {   // down arc: tail -> head = parent -> child
      int e = a >> 1;
      int u = mu[e], v = mv[e];
      int head = (a & 1) ? u : v;
      int tail = (a & 1) ? v : u;
      int p = (NA - 1) - (int)r_a[a];
      int d = (int)tv[p];
      parentS[head] = (unsigned short)tail;
      depthS[head] = (unsigned short)d;
      atomicMax(&smaxd, d);
    }
  }
  if (tid == 0) { parentS[0] = 0; depthS[0] = 0; }
  __syncthreads();
  int maxd = smaxd;
  // ---- Phase D: counting sort by depth ----
  for (int d = tid; d <= VV; d += nt) { if (d < VV) ((int*)lev)[d] = 0; else lev[VV] = 0; }
  __syncthreads();
  for (int v = tid; v < VV; v += nt) atomicAdd(&lev[depthS[v]], 1);
  __syncthreads();
  {
    const int SCH = 7;
    int base = tid * SCH;
    int s = 0;
    #pragma unroll
    for (int k = 0; k < SCH; k++) { int d = base + k; if (d <= VV) s += lev[d]; }
    part[tid] = s;
    __syncthreads();
    for (int d = 1; d < 1024; d <<= 1) {
      int add = (tid >= d) ? part[tid - d] : 0;
      __syncthreads();
      part[tid] += add;
      __syncthreads();
    }
    int ex = part[tid] - s;
    #pragma unroll
    for (int k = 0; k < SCH; k++) {
      int d = base + k;
      if (d <= VV) {
        int st = ex;
        ex += lev[d];
        if (d < VV) cur[d] = st;
        lpG[t * (VV + 1) + d] = st;
      }
    }
  }
  __syncthreads();
  for (int v = tid; v < VV; v += nt) {
    int d = depthS[v];
    int slot = atomicAdd(&cur[d], 1);
    ordS[slot] = (unsigned short)v;
    posS[v] = (unsigned short)slot;
  }
  __syncthreads();
  for (int j = tid; j < VV; j += nt) {
    int v = ordS[j];
    int pv = parentS[v];
    ordG[t * VV + j] = v;
    pvG[t * VV + j] = pv;
    spG[t * VV + j] = posS[pv];
  }
  if (tid == 0) nlevG[t] = maxd + 1;
}

// ---------------- K5: per-position weight to parent, f32, BFS-sorted ----------------
__global__ void k_weights(const float* __restrict__ low, const float* __restrict__ high,
                          const int* __restrict__ ordG, const int* __restrict__ pvG,
                          float* __restrict__ wvp) {
  int i = blockIdx.x * blockDim.x + threadIdx.x;
  if (i >= TT * VV) return;
  int t = i / VV;
  int v = ordG[i], p = pvG[i];
  float d = 0.f;
  if (t < BB) {
    const float* emb = low + (size_t)t * CLOW * VV;
    for (int c = 0; c < CLOW; c++) { float x = emb[c * VV + v] - emb[c * VV + p]; d += x * x; }
  } else {
    const float* emb = high + (size_t)(t - BB) * CHIGH * VV;
    for (int c = 0; c < CHIGH; c++) { float x = emb[c * VV + v] - emb[c * VV + p]; d += x * x; }
  }
  wvp[i] = expf(-d / SIGMA_F);
}

// ---------------- K6: tree filter, one block per (tree,channel), LDS-resident ----------------
__global__ __launch_bounds__(256) void k_filter_pc(const float* __restrict__ Fsrc, float* __restrict__ Araw,
    const float* __restrict__ wvp, const int* __restrict__ ordG, const int* __restrict__ spG,
    const int* __restrict__ lpG, const int* __restrict__ nlevG, int treeBase) {
  int blk = blockIdx.x;
  int b = blk / CF, ch = blk - b * CF;
  int t = treeBase + b;
  __shared__ float S[VV];
  __shared__ float A[VV];
  __shared__ float w[VV];
  __shared__ unsigned short sp[VV];
  __shared__ int lpS[VV + 1];
  const int* ord = ordG + t * VV;
  const int* spt = spG + t * VV;
  const float* wsrc = wvp + t * VV;
  const int* lp = lpG + t * (VV + 1);
  int tid = threadIdx.x, nt = blockDim.x;
  int NL = nlevG[t];
  for (int j = tid; j <= NL; j += nt) lpS[j] = lp[j];
  const bool norm_in = (treeBase != 0);
  for (int j = tid; j < VV; j += nt) {
    sp[j] = (unsigned short)spt[j];
    w[j] = wsrc[j];
    float val;
    if (ch < CP) {
      int v = ord[j];
      if (!norm_in) val = Fsrc[((size_t)b * CP + ch) * VV + v];
      else          val = Fsrc[((size_t)b * CF + ch) * VV + v] / Fsrc[((size_t)b * CF + CP) * VV + v];
    } else val = 1.0f;
    S[j] = val;
  }
  __syncthreads();
  for (int l = NL - 1; l >= 1; l--) {
    int s0 = lpS[l], s1 = lpS[l + 1];
    for (int j = s0 + tid; j < s1; j += nt) {
      atomicAdd(&S[sp[j]], w[j] * S[j]);
    }
    __syncthreads();
  }
  if (tid == 0) A[0] = S[0];
  __syncthreads();
  for (int l = 1; l < NL; l++) {
    int s0 = lpS[l], s1 = lpS[l + 1];
    for (int j = s0 + tid; j < s1; j += nt) {
      float wv = w[j], sv = S[j];
      A[j] = sv + wv * (A[sp[j]] - wv * sv);
    }
    __syncthreads();
  }
  float* Ob = Araw + ((size_t)b * CF + ch) * VV;
  for (int j = tid; j < VV; j += nt) Ob[ord[j]] = A[j];
}

// ---------------- K7: ROI-masked L1 loss reduction (fused normalize of stage 2) ----------------
__global__ void k_loss(const float* __restrict__ prob, const float* __restrict__ Araw2,
                       const int* __restrict__ roi, double* __restrict__ acc) {
  int i = blockIdx.x * blockDim.x + threadIdx.x;
  int tid = threadIdx.x;
  double s = 0.0, n = 0.0;
  if (i < BB * VV) {
    int b = i / VV, v = i - b * VV;
    if (roi[i] != 0) {
      n = 1.0;
      const float* pb = prob + (size_t)b * CP * VV + v;
      const float* ab = Araw2 + (size_t)b * CF * VV + v;
      float inv = 1.0f / ab[CP * VV];
      float ls = 0.f;
      #pragma unroll
      for (int c = 0; c < CP; c++) ls += fabsf(pb[c * VV] - ab[c * VV] * inv);
      s = (double)ls;
    }
  }
  __shared__ double rs[256], rn[256];
  rs[tid] = s; rn[tid] = n;
  __syncthreads();
  for (int d = 128; d > 0; d >>= 1) {
    if (tid < d) { rs[tid] += rs[tid + d]; rn[tid] += rn[tid + d]; }
    __syncthreads();
  }
  if (tid == 0) { atomicAdd(&acc[0], rs[0]); atomicAdd(&acc[1], rn[0]); }
}

__global__ void k_finalize(const double* __restrict__ acc, float* __restrict__ out) {
  out[0] = (acc[1] > 0.0) ? (float)(acc[0] / acc[1]) : 0.0f;
}

extern "C" void kernel_launch(void* const* d_in, const int* in_sizes, int n_in,
                              void* d_out, int out_size, void* d_ws, size_t ws_size,
                              hipStream_t stream) {
  const float* preds = (const float*)d_in[0];
  const float* low   = (const float*)d_in[1];
  const float* high  = (const float*)d_in[2];
  const int*   roi   = (const int*)d_in[3];
  float* out = (float*)d_out;

  char* w = (char*)d_ws;
  size_t off = 0;
  auto alloc = [&](size_t bytes) -> void* {
    void* p = w + off;
    off += (bytes + 255) & ~(size_t)255;
    return p;
  };
  float* prob  = (float*)alloc((size_t)BB * CP * VV * 4);
  float* Araw1 = (float*)alloc((size_t)BB * CF * VV * 4);
  float* Araw2 = (float*)alloc((size_t)BB * CF * VV * 4);
  unsigned long long* ekey = (unsigned long long*)alloc((size_t)TT * EE * 8);
  int* mstU = (int*)alloc((size_t)TT * VV * 4);
  int* mstV = (int*)alloc((size_t)TT * VV * 4);
  int* ordG = (int*)alloc((size_t)TT * VV * 4);
  int* spG  = (int*)alloc((size_t)TT * VV * 4);
  int* pvG  = (int*)alloc((size_t)TT * VV * 4);
  int* lpG  = (int*)alloc((size_t)TT * (VV + 1) * 4);
  int* nlev = (int*)alloc((size_t)TT * 4);
  float* wvp = (float*)alloc((size_t)TT * VV * 4);
  double* acc = (double*)alloc(16);

  hipMemsetAsync(acc, 0, 16, stream);

  k_softmax<<<(BB * VV + 255) / 256, 256, 0, stream>>>(preds, prob);
  k_edgekey<<<(TT * EE + 255) / 256, 256, 0, stream>>>(low, high, ekey);
  k_boruvka<<<TT, 1024, 0, stream>>>(ekey, mstU, mstV);
  k_buildtree<<<TT, 1024, 0, stream>>>(mstU, mstV, ordG, spG, pvG, lpG, nlev);
  k_weights<<<(TT * VV + 255) / 256, 256, 0, stream>>>(low, high, ordG, pvG, wvp);
  k_filter_pc<<<BB * CF, 256, 0, stream>>>(prob,  Araw1, wvp, ordG, spG, lpG, nlev, 0);
  k_filter_pc<<<BB * CF, 256, 0, stream>>>(Araw1, Araw2, wvp, ordG, spG, lpG, nlev, BB);
  k_loss<<<(BB * VV + 255) / 256, 256, 0, stream>>>(prob, Araw2, roi, acc);
  k_finalize<<<1, 1, 0, stream>>>(acc, out);
}

// Round 4
// 565.252 us; speedup vs baseline: 4.7854x; 1.0587x over previous
//
#include <hip/hip_runtime.h>

#define BB 8
#define CP 21
#define CF 22
#define CLOW 3
#define CHIGH 256
#define WW 80
#define VV 6400
#define EVERT 6320
#define EE 12640
#define TT 16
#define SIGMA_F 0.002f
#define ROOT 3240          // grid center (40,40): halves tree eccentricity vs corner

#define NE (VV - 1)        // tree edges
#define NA (2 * NE)        // Euler arcs = 12798
#define NILA 0xFFFFu

__device__ __forceinline__ void edge_uv(int e, int& u, int& v) {
  if (e < EVERT) { u = e; v = e + WW; }
  else { int e2 = e - EVERT; int r = e2 / (WW - 1); int c = e2 - r * (WW - 1); u = r * WW + c; v = u + 1; }
}

// ---------------- K1: softmax over 21 channels, per pixel ----------------
__global__ void k_softmax(const float* __restrict__ preds, float* __restrict__ prob) {
  int i = blockIdx.x * blockDim.x + threadIdx.x;
  if (i >= BB * VV) return;
  int b = i / VV, v = i - b * VV;
  const float* p = preds + (size_t)b * CP * VV + v;
  float m = -1e30f;
  #pragma unroll
  for (int c = 0; c < CP; c++) m = fmaxf(m, p[c * VV]);
  float e[CP], s = 0.f;
  #pragma unroll
  for (int c = 0; c < CP; c++) { float x = expf(p[c * VV] - m); e[c] = x; s += x; }
  float inv = 1.f / s;
  float* o = prob + (size_t)b * CP * VV + v;
  #pragma unroll
  for (int c = 0; c < CP; c++) o[c * VV] = e[c] * inv;
}

// ---------------- K2: edge keys (float64 cost, top-50-bits | edge idx) ----------------
__global__ void k_edgekey(const float* __restrict__ low, const float* __restrict__ high,
                          unsigned long long* __restrict__ ekey) {
  int i = blockIdx.x * blockDim.x + threadIdx.x;
  if (i >= TT * EE) return;
  int t = i / EE, e = i - t * EE;
  int u, v; edge_uv(e, u, v);
  double acc = 0.0;
  if (t < BB) {
    const float* emb = low + (size_t)t * CLOW * VV;
    for (int c = 0; c < CLOW; c++) { double d = (double)emb[c * VV + u] - (double)emb[c * VV + v]; acc += d * d; }
  } else {
    const float* emb = high + (size_t)(t - BB) * CHIGH * VV;
    for (int c = 0; c < CHIGH; c++) { double d = (double)emb[c * VV + u] - (double)emb[c * VV + v]; acc += d * d; }
  }
  unsigned long long bits = (unsigned long long)__double_as_longlong(acc);
  ekey[i] = (bits & ~0x3FFFULL) | (unsigned long long)e;
}

// ---------------- K3: parallel Boruvka MST, one block per tree (best[] in LDS) ----------------
__global__ __launch_bounds__(1024) void k_boruvka(const unsigned long long* __restrict__ ekey,
    int* __restrict__ mstU, int* __restrict__ mstV) {
  int t = blockIdx.x;
  const unsigned long long* key = ekey + (size_t)t * EE;
  int* mu = mstU + t * VV;
  int* mv = mstV + t * VV;
  __shared__ int comp[VV];
  __shared__ int tgt[VV];
  __shared__ unsigned long long bst[VV];
  __shared__ int changed, moved, cnt;
  int tid = threadIdx.x, nt = blockDim.x;
  for (int v = tid; v < VV; v += nt) comp[v] = v;
  if (tid == 0) cnt = 0;
  __syncthreads();
  for (int round = 0; round < 48; round++) {
    for (int v = tid; v < VV; v += nt) bst[v] = ~0ULL;
    if (tid == 0) changed = 0;
    __syncthreads();
    for (int e = tid; e < EE; e += nt) {
      int u, v; edge_uv(e, u, v);
      int cu = comp[u], cv = comp[v];
      if (cu != cv) { unsigned long long k = key[e]; atomicMin(&bst[cu], k); atomicMin(&bst[cv], k); }
    }
    __syncthreads();
    for (int c = tid; c < VV; c += nt) {
      tgt[c] = -1;
      if (comp[c] != c) continue;
      unsigned long long k = bst[c];
      if (k == ~0ULL) continue;
      int e = (int)(k & 0x3FFFULL);
      int u, v; edge_uv(e, u, v);
      int cu = comp[u], cv = comp[v];
      tgt[c] = (cu == c) ? cv : cu;
    }
    __syncthreads();
    for (int c = tid; c < VV; c += nt) {
      int o = tgt[c];
      if (o < 0) continue;
      unsigned long long k = bst[c];
      if (bst[o] == k && c < o) continue;  // mutual minimum edge: smaller id stays root
      comp[c] = o;
      int slot = atomicAdd(&cnt, 1);
      int e = (int)(k & 0x3FFFULL);
      int u, v; edge_uv(e, u, v);
      mu[slot] = u; mv[slot] = v;
      changed = 1;
    }
    __syncthreads();
    if (!changed) break;
    for (int it = 0; it < 32; it++) {
      if (tid == 0) moved = 0;
      __syncthreads();
      for (int v = tid; v < VV; v += nt) {
        int c = comp[v]; int cc = comp[c];
        if (cc != c) { comp[v] = cc; moved = 1; }
      }
      __syncthreads();
      if (!moved) break;
    }
  }
}

// ---------------- K4: Euler-tour tree rooting at ROOT ----------------
__global__ __launch_bounds__(1024) void k_buildtree(const int* __restrict__ mstU, const int* __restrict__ mstV,
    int* __restrict__ ordG, int* __restrict__ spG, int* __restrict__ pvG,
    int* __restrict__ lpG, int* __restrict__ nlevG) {
  int t = blockIdx.x;
  const int* mu = mstU + t * VV;
  const int* mv = mstV + t * VV;
  int tid = threadIdx.x, nt = blockDim.x;

  __shared__ int buf4[32004];            // 128016-byte phase-overlapped arena
  char* buf = (char*)buf4;
  __shared__ int part[1024];
  __shared__ int lasts, smaxd;

  // Phase A regions
  int* deg = (int*)(buf + 0);                       // int[VV)            [0,25600)
  int* off = (int*)(buf + 25600);                   // int[VV+1]          [25600,51204)
  unsigned short* adjA = (unsigned short*)(buf + 51208);   // ushort[NA]  [51208,76804)
  unsigned short* succ = (unsigned short*)(buf + 76808);   // ushort[NA]  [76808,102404)
  // Phase B (ranking) regions
  unsigned short* r_a = (unsigned short*)(buf + 0);        // ushort[NA]
  unsigned short* r_b = (unsigned short*)(buf + 25604);    // ushort[NA]
  unsigned short* nx_b = (unsigned short*)(buf + 102408);  // ushort[NA]
  // Phase C regions
  short* tv = (short*)(buf + 51208);                       // short[NA]   (adjA dead)
  unsigned short* parentS = (unsigned short*)(buf + 76808);// ushort[VV]  (succ dead)
  unsigned short* depthS  = (unsigned short*)(buf + 89608);// ushort[VV]
  // Phase D regions
  int* lev = (int*)(buf + 0);                      // int[VV+1]  (r_a dead)
  int* cur = (int*)(buf + 25604);                  // int[VV]    (r_b dead)
  unsigned short* ordS = (unsigned short*)(buf + 102408);  // ushort[VV] (nx_b dead)
  unsigned short* posS = (unsigned short*)(buf + 115208);  // ushort[VV]

  // ---- Phase A: CSR + Euler successors ----
  for (int v = tid; v < VV; v += nt) deg[v] = 0;
  __syncthreads();
  for (int e = tid; e < NE; e += nt) { atomicAdd(&deg[mu[e]], 1); atomicAdd(&deg[mv[e]], 1); }
  __syncthreads();
  {
    const int SCH = 7;
    int base = tid * SCH;
    int s = 0;
    #pragma unroll
    for (int k = 0; k < SCH; k++) { int v = base + k; if (v < VV) s += deg[v]; }
    part[tid] = s;
    __syncthreads();
    for (int d = 1; d < 1024; d <<= 1) {
      int add = (tid >= d) ? part[tid - d] : 0;
      __syncthreads();
      part[tid] += add;
      __syncthreads();
    }
    int ex = part[tid] - s;
    #pragma unroll
    for (int k = 0; k < SCH; k++) { int v = base + k; if (v < VV) { off[v] = ex; ex += deg[v]; } }
    if (tid == 1023) off[VV] = ex;
  }
  __syncthreads();
  for (int v = tid; v < VV; v += nt) deg[v] = off[v];   // cursors
  __syncthreads();
  for (int e = tid; e < NE; e += nt) {
    int u = mu[e], v = mv[e];
    adjA[atomicAdd(&deg[u], 1)] = (unsigned short)(2 * e);       // arc u->v
    adjA[atomicAdd(&deg[v], 1)] = (unsigned short)(2 * e + 1);   // arc v->u
  }
  __syncthreads();
  for (int v = tid; v < VV; v += nt) {
    int b0 = off[v], dv = off[v + 1] - b0;
    for (int k = 0; k < dv; k++) {
      unsigned short a = adjA[b0 + k];
      unsigned short b = adjA[b0 + ((k + 1 == dv) ? 0 : k + 1)];
      succ[a ^ 1] = b;
    }
  }
  if (tid == 0) {
    lasts = adjA[off[ROOT] + (off[ROOT + 1] - off[ROOT]) - 1] ^ 1;  // last arc entering root
    smaxd = 0;
  }
  __syncthreads();
  if (tid == 0) succ[lasts] = (unsigned short)NILA;
  __syncthreads();
  // ---- Phase B: list ranking (r = #arcs strictly after) ----
  for (int a = tid; a < NA; a += nt) r_a[a] = (succ[a] == (unsigned short)NILA) ? 0 : 1;
  __syncthreads();
  {
    unsigned short *rx = r_a, *ry = r_b, *nxp = succ, *nyp = nx_b;
    for (int rd = 0; rd < 14; rd++) {
      for (int a = tid; a < NA; a += nt) {
        unsigned short n = nxp[a];
        if (n == (unsigned short)NILA) { ry[a] = rx[a]; nyp[a] = (unsigned short)NILA; }
        else { ry[a] = rx[a] + rx[n]; nyp[a] = nxp[n]; }
      }
      __syncthreads();
      unsigned short* tp;
      tp = rx; rx = ry; ry = tp;
      tp = nxp; nxp = nyp; nyp = tp;
    }
    // 14 rounds (even) -> final ranks in r_a
  }
  // ---- Phase C: tour values, depth scan, parent extraction ----
  for (int a = tid; a < NA; a += nt) {
    int p = (NA - 1) - (int)r_a[a];
    tv[p] = (r_a[a] > r_a[a ^ 1]) ? (short)1 : (short)-1;
  }
  __syncthreads();
  {
    const int SCH = 13;
    int base = tid * SCH;
    int lim = base + SCH; if (lim > NA) lim = NA;
    int s = 0;
    for (int j = base; j < lim; j++) s += tv[j];
    part[tid] = s;
    __syncthreads();
    for (int d = 1; d < 1024; d <<= 1) {
      int add = (tid >= d) ? part[tid - d] : 0;
      __syncthreads();
      part[tid] += add;
      __syncthreads();
    }
    int run = part[tid] - s;
    for (int j = base; j < lim; j++) { run += tv[j]; tv[j] = (short)run; }
  }
  __syncthreads();
  for (int a = tid; a < NA; a += nt) {
    if (r_a[a] > r_a[a ^ 1]) {   // down arc: tail -> head = parent -> child
      int e = a >> 1;
      int u = mu[e], v = mv[e];
      int head = (a & 1) ? u : v;
      int tail = (a & 1) ? v : u;
      int p = (NA - 1) - (int)r_a[a];
      int d = (int)tv[p];
      parentS[head] = (unsigned short)tail;
      depthS[head] = (unsigned short)d;
      atomicMax(&smaxd, d);
    }
  }
  if (tid == 0) { parentS[ROOT] = ROOT; depthS[ROOT] = 0; }
  __syncthreads();
  int maxd = smaxd;
  // ---- Phase D: counting sort by depth ----
  for (int d = tid; d <= VV; d += nt) lev[d] = 0;
  __syncthreads();
  for (int v = tid; v < VV; v += nt) atomicAdd(&lev[depthS[v]], 1);
  __syncthreads();
  {
    const int SCH = 7;
    int base = tid * SCH;
    int s = 0;
    #pragma unroll
    for (int k = 0; k < SCH; k++) { int d = base + k; if (d <= VV) s += lev[d]; }
    part[tid] = s;
    __syncthreads();
    for (int d = 1; d < 1024; d <<= 1) {
      int add = (tid >= d) ? part[tid - d] : 0;
      __syncthreads();
      part[tid] += add;
      __syncthreads();
    }
    int ex = part[tid] - s;
    #pragma unroll
    for (int k = 0; k < SCH; k++) {
      int d = base + k;
      if (d <= VV) {
        int st = ex;
        ex += lev[d];
        if (d < VV) cur[d] = st;
        lpG[t * (VV + 1) + d] = st;
      }
    }
  }
  __syncthreads();
  for (int v = tid; v < VV; v += nt) {
    int d = depthS[v];
    int slot = atomicAdd(&cur[d], 1);
    ordS[slot] = (unsigned short)v;
    posS[v] = (unsigned short)slot;
  }
  __syncthreads();
  for (int j = tid; j < VV; j += nt) {
    int v = ordS[j];
    int pv = parentS[v];
    ordG[t * VV + j] = v;
    pvG[t * VV + j] = pv;
    spG[t * VV + j] = posS[pv];
  }
  if (tid == 0) nlevG[t] = maxd + 1;
}

// ---------------- K5: per-position weight to parent, O(1) via edge-key reuse ----------------
// (v,parent) is always a grid edge; its f64 cost is in ekey (low 14 mantissa bits zeroed
//  by the edge-id tag: relative error 2^-38, negligible).
__global__ void k_weights(const unsigned long long* __restrict__ ekey,
                          const int* __restrict__ ordG, const int* __restrict__ pvG,
                          float* __restrict__ wvp) {
  int i = blockIdx.x * blockDim.x + threadIdx.x;
  if (i >= TT * VV) return;
  int t = i / VV;
  int v = ordG[i], p = pvG[i];
  float wout;
  if (v == p) {
    wout = 1.0f;  // root (unused by sweeps)
  } else {
    int a = v < p ? v : p;
    int diff = v < p ? p - v : v - p;
    int e;
    if (diff == WW) e = a;                                        // vertical edge
    else { int r = a / WW, c = a - r * WW; e = EVERT + r * (WW - 1) + c; }  // horizontal
    unsigned long long k = ekey[(size_t)t * EE + e];
    double cost = __longlong_as_double((long long)(k & ~0x3FFFULL));
    wout = expf(-(float)cost / SIGMA_F);
  }
  wvp[i] = wout;
}

// ---------------- K6: tree filter, one SINGLE-WAVE block per (tree,channel) ----------------
// 64-thread blocks: s_barrier degenerates (1 wave), per-level cost = LDS dependency only.
// Down-sweep is in-place over S (parents finalized before children read them).
__global__ __launch_bounds__(64) void k_filter_pc(const float* __restrict__ Fsrc, float* __restrict__ Araw,
    const float* __restrict__ wvp, const int* __restrict__ ordG, const int* __restrict__ spG,
    const int* __restrict__ lpG, const int* __restrict__ nlevG, int treeBase) {
  int blk = blockIdx.x;
  int b = blk / CF, ch = blk - b * CF;
  int t = treeBase + b;
  __shared__ float S[VV];
  __shared__ float w[VV];
  __shared__ unsigned short sp[VV];
  __shared__ int lpS[VV + 1];
  const int* ord = ordG + t * VV;
  const int* spt = spG + t * VV;
  const float* wsrc = wvp + t * VV;
  const int* lp = lpG + t * (VV + 1);
  int tid = threadIdx.x;
  int NL = nlevG[t];
  for (int j = tid; j <= NL; j += 64) lpS[j] = lp[j];
  const bool norm_in = (treeBase != 0);
  for (int j = tid; j < VV; j += 64) {
    sp[j] = (unsigned short)spt[j];
    w[j] = wsrc[j];
    float val;
    if (ch < CP) {
      int v = ord[j];
      if (!norm_in) val = Fsrc[((size_t)b * CP + ch) * VV + v];
      else          val = Fsrc[((size_t)b * CF + ch) * VV + v] / Fsrc[((size_t)b * CF + CP) * VV + v];
    } else val = 1.0f;
    S[j] = val;
  }
  __syncthreads();
  // up-sweep
  for (int l = NL - 1; l >= 1; l--) {
    int s0 = lpS[l], s1 = lpS[l + 1];
    for (int j = s0 + tid; j < s1; j += 64) {
      atomicAdd(&S[sp[j]], w[j] * S[j]);
    }
    __syncthreads();
  }
  // down-sweep in place: S[j] <- A[j]
  for (int l = 1; l < NL; l++) {
    int s0 = lpS[l], s1 = lpS[l + 1];
    for (int j = s0 + tid; j < s1; j += 64) {
      float wv = w[j], sv = S[j];
      S[j] = sv + wv * (S[sp[j]] - wv * sv);
    }
    __syncthreads();
  }
  float* Ob = Araw + ((size_t)b * CF + ch) * VV;
  for (int j = tid; j < VV; j += 64) Ob[ord[j]] = S[j];
}

// ---------------- K7: ROI-masked L1 loss reduction (fused normalize of stage 2) ----------------
__global__ void k_loss(const float* __restrict__ prob, const float* __restrict__ Araw2,
                       const int* __restrict__ roi, double* __restrict__ acc) {
  int i = blockIdx.x * blockDim.x + threadIdx.x;
  int tid = threadIdx.x;
  double s = 0.0, n = 0.0;
  if (i < BB * VV) {
    int b = i / VV, v = i - b * VV;
    if (roi[i] != 0) {
      n = 1.0;
      const float* pb = prob + (size_t)b * CP * VV + v;
      const float* ab = Araw2 + (size_t)b * CF * VV + v;
      float inv = 1.0f / ab[CP * VV];
      float ls = 0.f;
      #pragma unroll
      for (int c = 0; c < CP; c++) ls += fabsf(pb[c * VV] - ab[c * VV] * inv);
      s = (double)ls;
    }
  }
  __shared__ double rs[256], rn[256];
  rs[tid] = s; rn[tid] = n;
  __syncthreads();
  for (int d = 128; d > 0; d >>= 1) {
    if (tid < d) { rs[tid] += rs[tid + d]; rn[tid] += rn[tid + d]; }
    __syncthreads();
  }
  if (tid == 0) { atomicAdd(&acc[0], rs[0]); atomicAdd(&acc[1], rn[0]); }
}

__global__ void k_finalize(const double* __restrict__ acc, float* __restrict__ out) {
  out[0] = (acc[1] > 0.0) ? (float)(acc[0] / acc[1]) : 0.0f;
}

extern "C" void kernel_launch(void* const* d_in, const int* in_sizes, int n_in,
                              void* d_out, int out_size, void* d_ws, size_t ws_size,
                              hipStream_t stream) {
  const float* preds = (const float*)d_in[0];
  const float* low   = (const float*)d_in[1];
  const float* high  = (const float*)d_in[2];
  const int*   roi   = (const int*)d_in[3];
  float* out = (float*)d_out;

  char* w = (char*)d_ws;
  size_t off = 0;
  auto alloc = [&](size_t bytes) -> void* {
    void* p = w + off;
    off += (bytes + 255) & ~(size_t)255;
    return p;
  };
  float* prob  = (float*)alloc((size_t)BB * CP * VV * 4);
  float* Araw1 = (float*)alloc((size_t)BB * CF * VV * 4);
  float* Araw2 = (float*)alloc((size_t)BB * CF * VV * 4);
  unsigned long long* ekey = (unsigned long long*)alloc((size_t)TT * EE * 8);
  int* mstU = (int*)alloc((size_t)TT * VV * 4);
  int* mstV = (int*)alloc((size_t)TT * VV * 4);
  int* ordG = (int*)alloc((size_t)TT * VV * 4);
  int* spG  = (int*)alloc((size_t)TT * VV * 4);
  int* pvG  = (int*)alloc((size_t)TT * VV * 4);
  int* lpG  = (int*)alloc((size_t)TT * (VV + 1) * 4);
  int* nlev = (int*)alloc((size_t)TT * 4);
  float* wvp = (float*)alloc((size_t)TT * VV * 4);
  double* acc = (double*)alloc(16);

  hipMemsetAsync(acc, 0, 16, stream);

  k_softmax<<<(BB * VV + 255) / 256, 256, 0, stream>>>(preds, prob);
  k_edgekey<<<(TT * EE + 255) / 256, 256, 0, stream>>>(low, high, ekey);
  k_boruvka<<<TT, 1024, 0, stream>>>(ekey, mstU, mstV);
  k_buildtree<<<TT, 1024, 0, stream>>>(mstU, mstV, ordG, spG, pvG, lpG, nlev);
  k_weights<<<(TT * VV + 255) / 256, 256, 0, stream>>>(ekey, ordG, pvG, wvp);
  k_filter_pc<<<BB * CF, 64, 0, stream>>>(prob,  Araw1, wvp, ordG, spG, lpG, nlev, 0);
  k_filter_pc<<<BB * CF, 64, 0, stream>>>(Araw1, Araw2, wvp, ordG, spG, lpG, nlev, BB);
  k_loss<<<(BB * VV + 255) / 256, 256, 0, stream>>>(prob, Araw2, roi, acc);
  k_finalize<<<1, 1, 0, stream>>>(acc, out);
}

// Round 5
// 418.945 us; speedup vs baseline: 6.4566x; 1.3492x over previous
//
#include <hip/hip_runtime.h>

#define BB 8
#define CP 21
#define CF 22
#define CLOW 3
#define CHIGH 256
#define WW 80
#define VV 6400
#define EVERT 6320
#define EE 12640
#define TT 16
#define SIGMA_F 0.002f
#define ROOT 3240          // grid center (40,40): halves tree eccentricity vs corner

#define NE (VV - 1)        // tree edges
#define NA (2 * NE)        // Euler arcs = 12798
#define NILA 0xFFFFu

__device__ __forceinline__ void edge_uv(int e, int& u, int& v) {
  if (e < EVERT) { u = e; v = e + WW; }
  else { int e2 = e - EVERT; int r = e2 / (WW - 1); int c = e2 - r * (WW - 1); u = r * WW + c; v = u + 1; }
}

// ---------------- K1: softmax over 21 channels, per pixel ----------------
__global__ void k_softmax(const float* __restrict__ preds, float* __restrict__ prob) {
  int i = blockIdx.x * blockDim.x + threadIdx.x;
  if (i >= BB * VV) return;
  int b = i / VV, v = i - b * VV;
  const float* p = preds + (size_t)b * CP * VV + v;
  float m = -1e30f;
  #pragma unroll
  for (int c = 0; c < CP; c++) m = fmaxf(m, p[c * VV]);
  float e[CP], s = 0.f;
  #pragma unroll
  for (int c = 0; c < CP; c++) { float x = expf(p[c * VV] - m); e[c] = x; s += x; }
  float inv = 1.f / s;
  float* o = prob + (size_t)b * CP * VV + v;
  #pragma unroll
  for (int c = 0; c < CP; c++) o[c * VV] = e[c] * inv;
}

// ---------------- K2: edge keys (float64 cost, top-50-bits | edge idx) ----------------
__global__ void k_edgekey(const float* __restrict__ low, const float* __restrict__ high,
                          unsigned long long* __restrict__ ekey) {
  int i = blockIdx.x * blockDim.x + threadIdx.x;
  if (i >= TT * EE) return;
  int t = i / EE, e = i - t * EE;
  int u, v; edge_uv(e, u, v);
  double acc = 0.0;
  if (t < BB) {
    const float* emb = low + (size_t)t * CLOW * VV;
    for (int c = 0; c < CLOW; c++) { double d = (double)emb[c * VV + u] - (double)emb[c * VV + v]; acc += d * d; }
  } else {
    const float* emb = high + (size_t)(t - BB) * CHIGH * VV;
    for (int c = 0; c < CHIGH; c++) { double d = (double)emb[c * VV + u] - (double)emb[c * VV + v]; acc += d * d; }
  }
  unsigned long long bits = (unsigned long long)__double_as_longlong(acc);
  ekey[i] = (bits & ~0x3FFFULL) | (unsigned long long)e;
}

// ---------------- K3: parallel Boruvka MST, one block per tree (best[] in LDS) ----------------
__global__ __launch_bounds__(1024) void k_boruvka(const unsigned long long* __restrict__ ekey,
    int* __restrict__ mstU, int* __restrict__ mstV) {
  int t = blockIdx.x;
  const unsigned long long* key = ekey + (size_t)t * EE;
  int* mu = mstU + t * VV;
  int* mv = mstV + t * VV;
  __shared__ int comp[VV];
  __shared__ int tgt[VV];
  __shared__ unsigned long long bst[VV];
  __shared__ int changed, moved, cnt;
  int tid = threadIdx.x, nt = blockDim.x;
  for (int v = tid; v < VV; v += nt) comp[v] = v;
  if (tid == 0) cnt = 0;
  __syncthreads();
  for (int round = 0; round < 48; round++) {
    for (int v = tid; v < VV; v += nt) bst[v] = ~0ULL;
    if (tid == 0) changed = 0;
    __syncthreads();
    for (int e = tid; e < EE; e += nt) {
      int u, v; edge_uv(e, u, v);
      int cu = comp[u], cv = comp[v];
      if (cu != cv) { unsigned long long k = key[e]; atomicMin(&bst[cu], k); atomicMin(&bst[cv], k); }
    }
    __syncthreads();
    for (int c = tid; c < VV; c += nt) {
      tgt[c] = -1;
      if (comp[c] != c) continue;
      unsigned long long k = bst[c];
      if (k == ~0ULL) continue;
      int e = (int)(k & 0x3FFFULL);
      int u, v; edge_uv(e, u, v);
      int cu = comp[u], cv = comp[v];
      tgt[c] = (cu == c) ? cv : cu;
    }
    __syncthreads();
    for (int c = tid; c < VV; c += nt) {
      int o = tgt[c];
      if (o < 0) continue;
      unsigned long long k = bst[c];
      if (bst[o] == k && c < o) continue;  // mutual minimum edge: smaller id stays root
      comp[c] = o;
      int slot = atomicAdd(&cnt, 1);
      int e = (int)(k & 0x3FFFULL);
      int u, v; edge_uv(e, u, v);
      mu[slot] = u; mv[slot] = v;
      changed = 1;
    }
    __syncthreads();
    if (!changed) break;
    for (int it = 0; it < 32; it++) {
      if (tid == 0) moved = 0;
      __syncthreads();
      for (int v = tid; v < VV; v += nt) {
        int c = comp[v]; int cc = comp[c];
        if (cc != c) { comp[v] = cc; moved = 1; }
      }
      __syncthreads();
      if (!moved) break;
    }
  }
}

// ---------------- K4: Euler-tour tree rooting at ROOT ----------------
__global__ __launch_bounds__(1024) void k_buildtree(const int* __restrict__ mstU, const int* __restrict__ mstV,
    int* __restrict__ ordG, int* __restrict__ spG, int* __restrict__ pvG,
    int* __restrict__ lpG, int* __restrict__ nlevG) {
  int t = blockIdx.x;
  const int* mu = mstU + t * VV;
  const int* mv = mstV + t * VV;
  int tid = threadIdx.x, nt = blockDim.x;

  __shared__ int buf4[32004];            // 128016-byte phase-overlapped arena
  char* buf = (char*)buf4;
  __shared__ int part[1024];
  __shared__ int lasts, smaxd;

  // Phase A regions
  int* deg = (int*)(buf + 0);                       // int[VV)            [0,25600)
  int* off = (int*)(buf + 25600);                   // int[VV+1]          [25600,51204)
  unsigned short* adjA = (unsigned short*)(buf + 51208);   // ushort[NA]  [51208,76804)
  unsigned short* succ = (unsigned short*)(buf + 76808);   // ushort[NA]  [76808,102404)
  // Phase B (ranking) regions
  unsigned short* r_a = (unsigned short*)(buf + 0);        // ushort[NA]
  unsigned short* r_b = (unsigned short*)(buf + 25604);    // ushort[NA]
  unsigned short* nx_b = (unsigned short*)(buf + 102408);  // ushort[NA]
  // Phase C regions
  short* tv = (short*)(buf + 51208);                       // short[NA]   (adjA dead)
  unsigned short* parentS = (unsigned short*)(buf + 76808);// ushort[VV]  (succ dead)
  unsigned short* depthS  = (unsigned short*)(buf + 89608);// ushort[VV]
  // Phase D regions
  int* lev = (int*)(buf + 0);                      // int[VV+1]  (r_a dead)
  int* cur = (int*)(buf + 25604);                  // int[VV]    (r_b dead)
  unsigned short* ordS = (unsigned short*)(buf + 102408);  // ushort[VV] (nx_b dead)
  unsigned short* posS = (unsigned short*)(buf + 115208);  // ushort[VV]

  // ---- Phase A: CSR + Euler successors ----
  for (int v = tid; v < VV; v += nt) deg[v] = 0;
  __syncthreads();
  for (int e = tid; e < NE; e += nt) { atomicAdd(&deg[mu[e]], 1); atomicAdd(&deg[mv[e]], 1); }
  __syncthreads();
  {
    const int SCH = 7;
    int base = tid * SCH;
    int s = 0;
    #pragma unroll
    for (int k = 0; k < SCH; k++) { int v = base + k; if (v < VV) s += deg[v]; }
    part[tid] = s;
    __syncthreads();
    for (int d = 1; d < 1024; d <<= 1) {
      int add = (tid >= d) ? part[tid - d] : 0;
      __syncthreads();
      part[tid] += add;
      __syncthreads();
    }
    int ex = part[tid] - s;
    #pragma unroll
    for (int k = 0; k < SCH; k++) { int v = base + k; if (v < VV) { off[v] = ex; ex += deg[v]; } }
    if (tid == 1023) off[VV] = ex;
  }
  __syncthreads();
  for (int v = tid; v < VV; v += nt) deg[v] = off[v];   // cursors
  __syncthreads();
  for (int e = tid; e < NE; e += nt) {
    int u = mu[e], v = mv[e];
    adjA[atomicAdd(&deg[u], 1)] = (unsigned short)(2 * e);       // arc u->v
    adjA[atomicAdd(&deg[v], 1)] = (unsigned short)(2 * e + 1);   // arc v->u
  }
  __syncthreads();
  for (int v = tid; v < VV; v += nt) {
    int b0 = off[v], dv = off[v + 1] - b0;
    for (int k = 0; k < dv; k++) {
      unsigned short a = adjA[b0 + k];
      unsigned short b = adjA[b0 + ((k + 1 == dv) ? 0 : k + 1)];
      succ[a ^ 1] = b;
    }
  }
  if (tid == 0) {
    lasts = adjA[off[ROOT] + (off[ROOT + 1] - off[ROOT]) - 1] ^ 1;  // last arc entering root
    smaxd = 0;
  }
  __syncthreads();
  if (tid == 0) succ[lasts] = (unsigned short)NILA;
  __syncthreads();
  // ---- Phase B: list ranking (r = #arcs strictly after) ----
  for (int a = tid; a < NA; a += nt) r_a[a] = (succ[a] == (unsigned short)NILA) ? 0 : 1;
  __syncthreads();
  {
    unsigned short *rx = r_a, *ry = r_b, *nxp = succ, *nyp = nx_b;
    for (int rd = 0; rd < 14; rd++) {
      for (int a = tid; a < NA; a += nt) {
        unsigned short n = nxp[a];
        if (n == (unsigned short)NILA) { ry[a] = rx[a]; nyp[a] = (unsigned short)NILA; }
        else { ry[a] = rx[a] + rx[n]; nyp[a] = nxp[n]; }
      }
      __syncthreads();
      unsigned short* tp;
      tp = rx; rx = ry; ry = tp;
      tp = nxp; nxp = nyp; nyp = tp;
    }
    // 14 rounds (even) -> final ranks in r_a
  }
  // ---- Phase C: tour values, depth scan, parent extraction ----
  for (int a = tid; a < NA; a += nt) {
    int p = (NA - 1) - (int)r_a[a];
    tv[p] = (r_a[a] > r_a[a ^ 1]) ? (short)1 : (short)-1;
  }
  __syncthreads();
  {
    const int SCH = 13;
    int base = tid * SCH;
    int lim = base + SCH; if (lim > NA) lim = NA;
    int s = 0;
    for (int j = base; j < lim; j++) s += tv[j];
    part[tid] = s;
    __syncthreads();
    for (int d = 1; d < 1024; d <<= 1) {
      int add = (tid >= d) ? part[tid - d] : 0;
      __syncthreads();
      part[tid] += add;
      __syncthreads();
    }
    int run = part[tid] - s;
    for (int j = base; j < lim; j++) { run += tv[j]; tv[j] = (short)run; }
  }
  __syncthreads();
  for (int a = tid; a < NA; a += nt) {
    if (r_a[a] > r_a[a ^ 1]) {   // down arc: tail -> head = parent -> child
      int e = a >> 1;
      int u = mu[e], v = mv[e];
      int head = (a & 1) ? u : v;
      int tail = (a & 1) ? v : u;
      int p = (NA - 1) - (int)r_a[a];
      int d = (int)tv[p];
      parentS[head] = (unsigned short)tail;
      depthS[head] = (unsigned short)d;
      atomicMax(&smaxd, d);
    }
  }
  if (tid == 0) { parentS[ROOT] = ROOT; depthS[ROOT] = 0; }
  __syncthreads();
  int maxd = smaxd;
  // ---- Phase D: counting sort by depth ----
  for (int d = tid; d <= VV; d += nt) lev[d] = 0;
  __syncthreads();
  for (int v = tid; v < VV; v += nt) atomicAdd(&lev[depthS[v]], 1);
  __syncthreads();
  {
    const int SCH = 7;
    int base = tid * SCH;
    int s = 0;
    #pragma unroll
    for (int k = 0; k < SCH; k++) { int d = base + k; if (d <= VV) s += lev[d]; }
    part[tid] = s;
    __syncthreads();
    for (int d = 1; d < 1024; d <<= 1) {
      int add = (tid >= d) ? part[tid - d] : 0;
      __syncthreads();
      part[tid] += add;
      __syncthreads();
    }
    int ex = part[tid] - s;
    #pragma unroll
    for (int k = 0; k < SCH; k++) {
      int d = base + k;
      if (d <= VV) {
        int st = ex;
        ex += lev[d];
        if (d < VV) cur[d] = st;
        lpG[t * (VV + 1) + d] = st;
      }
    }
  }
  __syncthreads();
  for (int v = tid; v < VV; v += nt) {
    int d = depthS[v];
    int slot = atomicAdd(&cur[d], 1);
    ordS[slot] = (unsigned short)v;
    posS[v] = (unsigned short)slot;
  }
  __syncthreads();
  for (int j = tid; j < VV; j += nt) {
    int v = ordS[j];
    int pv = parentS[v];
    ordG[t * VV + j] = v;
    pvG[t * VV + j] = pv;
    spG[t * VV + j] = posS[pv];
  }
  if (tid == 0) nlevG[t] = maxd + 1;
}

// ---------------- K5: per-position weight to parent, O(1) via edge-key reuse ----------------
__global__ void k_weights(const unsigned long long* __restrict__ ekey,
                          const int* __restrict__ ordG, const int* __restrict__ pvG,
                          float* __restrict__ wvp) {
  int i = blockIdx.x * blockDim.x + threadIdx.x;
  if (i >= TT * VV) return;
  int t = i / VV;
  int v = ordG[i], p = pvG[i];
  float wout;
  if (v == p) {
    wout = 1.0f;  // root (overridden in filter)
  } else {
    int a = v < p ? v : p;
    int diff = v < p ? p - v : v - p;
    int e;
    if (diff == WW) e = a;                                        // vertical edge
    else { int r = a / WW, c = a - r * WW; e = EVERT + r * (WW - 1) + c; }  // horizontal
    unsigned long long k = ekey[(size_t)t * EE + e];
    double cost = __longlong_as_double((long long)(k & ~0x3FFFULL));
    wout = expf(-(float)cost / SIGMA_F);
  }
  wvp[i] = wout;
}

// ---------------- K6: tree filter — phase-resourced ----------------
// 256 threads: bulk load/scatter at 4 waves; up-sweep by wave 0 only (no s_barrier,
// explicit lgkmcnt waits); down-sweep via affine pointer doubling (log2(NL) rounds).
__global__ __launch_bounds__(256) void k_filter_pc(const float* __restrict__ Fsrc, float* __restrict__ Araw,
    const float* __restrict__ wvp, const int* __restrict__ ordG, const int* __restrict__ spG,
    const int* __restrict__ lpG, const int* __restrict__ nlevG, int treeBase) {
  int blk = blockIdx.x;
  int b = blk / CF, ch = blk - b * CF;
  int t = treeBase + b;
  __shared__ float S[VV];                 // up-sums -> b0 (in place)
  __shared__ float w[VV];                 // weights -> a0 (in place)
  __shared__ float a1[VV];
  __shared__ float b1[VV];
  __shared__ unsigned short sp[VV];       // parent pos -> p0
  __shared__ unsigned short p1[VV];
  __shared__ unsigned short lpS[VV + 1];
  const int* ord = ordG + t * VV;
  const int* spt = spG + t * VV;
  const float* wsrc = wvp + t * VV;
  const int* lp = lpG + t * (VV + 1);
  int tid = threadIdx.x;
  int NL = nlevG[t];
  for (int j = tid; j <= NL; j += 256) lpS[j] = (unsigned short)lp[j];
  const bool norm_in = (treeBase != 0);
  for (int j = tid; j < VV; j += 256) {
    sp[j] = (unsigned short)spt[j];
    w[j] = wsrc[j];
    float val;
    if (ch < CP) {
      int v = ord[j];
      if (!norm_in) val = Fsrc[((size_t)b * CP + ch) * VV + v];
      else          val = Fsrc[((size_t)b * CF + ch) * VV + v] / Fsrc[((size_t)b * CF + CP) * VV + v];
    } else val = 1.0f;
    S[j] = val;
  }
  __syncthreads();
  // ---- up-sweep: wave 0 only, barrier-free ----
  if (tid < 64) {
    for (int l = NL - 1; l >= 1; l--) {
      int s0 = lpS[l], s1 = lpS[l + 1];
      for (int j = s0 + tid; j < s1; j += 64) {
        atomicAdd(&S[sp[j]], w[j] * S[j]);
      }
      asm volatile("s_waitcnt lgkmcnt(0)" ::: "memory");
      __builtin_amdgcn_sched_barrier(0);
    }
  }
  __syncthreads();
  // ---- transform to affine (a0=w, b0=S in place); root at position 0 ----
  for (int j = tid; j < VV; j += 256) {
    if (j == 0) { w[0] = 0.f; }               // b0[0] stays S[0] = A[root]
    else { float wv = w[j]; S[j] = S[j] * (1.f - wv * wv); }
  }
  __syncthreads();
  // ---- down-sweep: pointer doubling over (p, a, b) ----
  int rounds = 0;
  { int d = 1; while (d < NL) { d <<= 1; rounds++; } }   // 2^rounds >= NL > maxdepth
  float *as_ = w, *bs_ = S, *ad_ = a1, *bd_ = b1;
  unsigned short *ps_ = sp, *pd_ = p1;
  for (int r = 0; r < rounds; r++) {
    for (int j = tid; j < VV; j += 256) {
      int p = ps_[j];
      float av = as_[j];
      pd_[j] = ps_[p];
      ad_[j] = av * as_[p];
      bd_[j] = av * bs_[p] + bs_[j];
    }
    __syncthreads();
    float* tf; unsigned short* tu;
    tf = as_; as_ = ad_; ad_ = tf;
    tf = bs_; bs_ = bd_; bd_ = tf;
    tu = ps_; ps_ = pd_; pd_ = tu;
  }
  // ---- scatter to vertex space (bs_ holds A) ----
  float* Ob = Araw + ((size_t)b * CF + ch) * VV;
  for (int j = tid; j < VV; j += 256) Ob[ord[j]] = bs_[j];
}

// ---------------- K7: ROI-masked L1 loss reduction (fused normalize of stage 2) ----------------
__global__ void k_loss(const float* __restrict__ prob, const float* __restrict__ Araw2,
                       const int* __restrict__ roi, double* __restrict__ acc) {
  int i = blockIdx.x * blockDim.x + threadIdx.x;
  int tid = threadIdx.x;
  double s = 0.0, n = 0.0;
  if (i < BB * VV) {
    int b = i / VV, v = i - b * VV;
    if (roi[i] != 0) {
      n = 1.0;
      const float* pb = prob + (size_t)b * CP * VV + v;
      const float* ab = Araw2 + (size_t)b * CF * VV + v;
      float inv = 1.0f / ab[CP * VV];
      float ls = 0.f;
      #pragma unroll
      for (int c = 0; c < CP; c++) ls += fabsf(pb[c * VV] - ab[c * VV] * inv);
      s = (double)ls;
    }
  }
  __shared__ double rs[256], rn[256];
  rs[tid] = s; rn[tid] = n;
  __syncthreads();
  for (int d = 128; d > 0; d >>= 1) {
    if (tid < d) { rs[tid] += rs[tid + d]; rn[tid] += rn[tid + d]; }
    __syncthreads();
  }
  if (tid == 0) { atomicAdd(&acc[0], rs[0]); atomicAdd(&acc[1], rn[0]); }
}

__global__ void k_finalize(const double* __restrict__ acc, float* __restrict__ out) {
  out[0] = (acc[1] > 0.0) ? (float)(acc[0] / acc[1]) : 0.0f;
}

extern "C" void kernel_launch(void* const* d_in, const int* in_sizes, int n_in,
                              void* d_out, int out_size, void* d_ws, size_t ws_size,
                              hipStream_t stream) {
  const float* preds = (const float*)d_in[0];
  const float* low   = (const float*)d_in[1];
  const float* high  = (const float*)d_in[2];
  const int*   roi   = (const int*)d_in[3];
  float* out = (float*)d_out;

  char* w = (char*)d_ws;
  size_t off = 0;
  auto alloc = [&](size_t bytes) -> void* {
    void* p = w + off;
    off += (bytes + 255) & ~(size_t)255;
    return p;
  };
  float* prob  = (float*)alloc((size_t)BB * CP * VV * 4);
  float* Araw1 = (float*)alloc((size_t)BB * CF * VV * 4);
  float* Araw2 = (float*)alloc((size_t)BB * CF * VV * 4);
  unsigned long long* ekey = (unsigned long long*)alloc((size_t)TT * EE * 8);
  int* mstU = (int*)alloc((size_t)TT * VV * 4);
  int* mstV = (int*)alloc((size_t)TT * VV * 4);
  int* ordG = (int*)alloc((size_t)TT * VV * 4);
  int* spG  = (int*)alloc((size_t)TT * VV * 4);
  int* pvG  = (int*)alloc((size_t)TT * VV * 4);
  int* lpG  = (int*)alloc((size_t)TT * (VV + 1) * 4);
  int* nlev = (int*)alloc((size_t)TT * 4);
  float* wvp = (float*)alloc((size_t)TT * VV * 4);
  double* acc = (double*)alloc(16);

  hipMemsetAsync(acc, 0, 16, stream);

  k_softmax<<<(BB * VV + 255) / 256, 256, 0, stream>>>(preds, prob);
  k_edgekey<<<(TT * EE + 255) / 256, 256, 0, stream>>>(low, high, ekey);
  k_boruvka<<<TT, 1024, 0, stream>>>(ekey, mstU, mstV);
  k_buildtree<<<TT, 1024, 0, stream>>>(mstU, mstV, ordG, spG, pvG, lpG, nlev);
  k_weights<<<(TT * VV + 255) / 256, 256, 0, stream>>>(ekey, ordG, pvG, wvp);
  k_filter_pc<<<BB * CF, 256, 0, stream>>>(prob,  Araw1, wvp, ordG, spG, lpG, nlev, 0);
  k_filter_pc<<<BB * CF, 256, 0, stream>>>(Araw1, Araw2, wvp, ordG, spG, lpG, nlev, BB);
  k_loss<<<(BB * VV + 255) / 256, 256, 0, stream>>>(prob, Araw2, roi, acc);
  k_finalize<<<1, 1, 0, stream>>>(acc, out);
}